// Round 10
// baseline (248.017 us; speedup 1.0000x reference)
//
#include <hip/hip_runtime.h>

static constexpr float kIouT = 0.35f;
static constexpr float kScoreT = 0.5f;
static constexpr int kMaxKeep = 512;

// Decision-exact "iou > T" vs the reference:
//   ref: inter = max(iy2-iy1,0)*max(ix2-ix1,0); iou = uni>0 ? inter/uni : 0.
// If dy<=0 or dx<=0 -> inter==0 -> iou==0 <= T  (quick reject, no division).
// Else inter=__fmul_rn(dy,dx) identical to ref; division kept for exactness.
__device__ __forceinline__ bool iou_gt(const float4 a, const float4 b) {
  const float iy1 = fmaxf(a.x, b.x), ix1 = fmaxf(a.y, b.y);
  const float iy2 = fminf(a.z, b.z), ix2 = fminf(a.w, b.w);
  const float dy = iy2 - iy1, dx = ix2 - ix1;
  if (!(dy > 0.0f && dx > 0.0f)) return false;
  const float inter = __fmul_rn(dy, dx);
  const float aA = __fmul_rn(a.z - a.x, a.w - a.y);
  const float aB = __fmul_rn(b.z - b.x, b.w - b.y);
  const float uni = (aA + aB) - inter;
  return (uni > 0.0f) && (__fdiv_rn(inter, uni) > kIouT);
}

// 64-bit cross-lane pull with UNIFORM lane index (v_readlane, no LDS crossbar).
__device__ __forceinline__ unsigned long long rdlane64(unsigned long long v,
                                                       int l) {
  unsigned lo = (unsigned)__builtin_amdgcn_readlane((int)(unsigned)v, l);
  unsigned hi = (unsigned)__builtin_amdgcn_readlane((int)(unsigned)(v >> 32), l);
  return ((unsigned long long)hi << 32) | lo;
}

// ------- kernel 1 — rank (counting) sort of the VALID prefix (+count fold) ----
// [proven form] Blocks [0, rankBlocks): one wave per row. For valid row i:
// rank = #{j: s_j > s_i} + #{j: s_j==s_i, j<i}. Invalid j (s<=0.5) sort after
// every valid i, so counting over ALL j gives the stable-descending position.
// Blocks [rankBlocks, rankBlocks+B): per-image valid count -> Mcnt.
__global__ __launch_bounds__(256)
void nms_rank_kernel(const float* __restrict__ scores,
                     const float4* __restrict__ boxes,
                     unsigned long long* __restrict__ skeys,
                     float4* __restrict__ sboxes,
                     int* __restrict__ Mcnt, int N, int rankBlocks) {
  const int tid = threadIdx.x;
  const int lane = tid & 63;
  if ((int)blockIdx.x >= rankBlocks) {   // ---- count mode ----
    __shared__ int part[4];
    const int img = blockIdx.x - rankBlocks;
    const int wv = tid >> 6;
    const float4* sc4 = (const float4*)(scores + (size_t)img * N);
    int c = 0;
    for (int q = tid; q < (N >> 2); q += 256) {
      float4 v = sc4[q];
      c += (v.x > kScoreT) + (v.y > kScoreT) + (v.z > kScoreT) + (v.w > kScoreT);
    }
#pragma unroll
    for (int off = 1; off < 64; off <<= 1) c += __shfl_xor(c, off, 64);
    if (lane == 0) part[wv] = c;
    __syncthreads();
    if (tid == 0) Mcnt[img] = part[0] + part[1] + part[2] + part[3];
    return;
  }
  // ---- rank mode ----
  const int wid = (int)(((unsigned)blockIdx.x * blockDim.x + tid) >> 6);
  const int img = wid / N;
  const int row = wid - img * N;
  const float* sc = scores + (size_t)img * N;
  const float si = sc[row];
  if (!(si > kScoreT)) return;
  const float4* sc4 = (const float4*)sc;
  int cnt = 0;
  for (int q = lane; q < (N >> 2); q += 64) {   // coalesced, L1/L2-resident
    const float4 v = sc4[q];
    const int j = q << 2;
    cnt += (v.x > si) + (v.y > si) + (v.z > si) + (v.w > si);
    if (v.x == si && j < row) cnt++;
    if (v.y == si && j + 1 < row) cnt++;
    if (v.z == si && j + 2 < row) cnt++;
    if (v.w == si && j + 3 < row) cnt++;
  }
#pragma unroll
  for (int off = 1; off < 64; off <<= 1) cnt += __shfl_xor(cnt, off, 64);
  if (lane == 0) {
    skeys[(size_t)img * N + cnt] =
        ((unsigned long long)(~__float_as_uint(si)) << 32) | (unsigned)row;
    sboxes[(size_t)img * N + cnt] = boxes[(size_t)img * N + row];
  }
}

// ------- kernel 2 — fused on-chip NMS (replaces mask matrix + scan) ----------
// One block per image, 512 threads. Thread t owns sorted candidates t+512k
// (boxes in registers). Per 64-candidate chunk:
//  A) owner wave stages chunk boxes + alive-ballot into LDS;
//  B) 8 waves compute the 64x64 self-mask (rows 8w..8w+7) into LDS;
//  C) wave 0 runs the scalar readlane greedy on the diag, appends kept
//     boxes/indices to LDS keptbox/keptlist (parallel rank-compaction);
//  D) all threads filter their future register candidates vs the NEWLY kept
//     boxes (LDS broadcast reads). No global memory in the recurrence.
__global__ __launch_bounds__(512, 1)
void nms_keep_kernel(const unsigned long long* __restrict__ skeys,
                     const float4* __restrict__ sboxes,
                     const int* __restrict__ Mcnt,
                     const float* __restrict__ anchors,
                     float* __restrict__ out, int N, int NS) {
  __shared__ float4 keptbox[kMaxKeep];          // 8 KiB
  __shared__ int keptlist[kMaxKeep];            // 2 KiB
  __shared__ float4 chunkbox[64];               // 1 KiB
  __shared__ unsigned long long smask[64];      // 512 B
  __shared__ unsigned long long s_ca;
  __shared__ int s_kept;
  const int img = blockIdx.x;
  const int tid = threadIdx.x;
  const int lane = tid & 63;
  const int wv = tid >> 6;
  int m = Mcnt[img];
  if (m > N) m = N;
  if (m < 0) m = 0;
  const unsigned long long* kg = skeys + (size_t)img * N;
  const float4* sb = sboxes + (size_t)img * N;
  const float* an = anchors + (size_t)img * (size_t)N * 4;
  float* o = out + (size_t)img * NS * 7;

  // register-resident owned candidates (static indexing only)
  float4 obox[8];
  unsigned alivebits = 0u;
#pragma unroll
  for (int k = 0; k < 8; ++k) {
    const int idx = tid + (k << 9);
    if (idx < m) { obox[k] = sb[idx]; alivebits |= 1u << k; }
  }
  if (tid == 0) s_kept = 0;
  __syncthreads();

  int kept = 0;
  for (int base = 0; base < m && kept < NS; base += 64) {
    const int ow = (base >> 6) & 7;          // owner wave of this chunk
    const int slot = base >> 9;              // register slot (uniform)
    // ---- A: stage chunk ----
    if (wv == ow) {
      float4 cb = obox[0];
#pragma unroll
      for (int k = 1; k < 8; ++k)
        if (k == slot) cb = obox[k];         // uniform select, stays in regs
      chunkbox[lane] = cb;
      const bool al = (alivebits >> slot) & 1u;
      const unsigned long long bm = __ballot(al);
      if (lane == 0) s_ca = bm;
      alivebits &= ~(1u << slot);            // chunk is now processed
    }
    __syncthreads();
    const unsigned long long ca = s_ca;
    if (ca != 0ull) {
      const int kbase = kept;
      // ---- B: self-mask rows (8 per wave) ----
      {
        const float4 cj = chunkbox[lane];
#pragma unroll
        for (int r = 0; r < 8; ++r) {
          const int row = (wv << 3) + r;
          const float4 bi = chunkbox[row];   // broadcast
          bool sup = false;
          if (lane > row) sup = iou_gt(bi, cj);
          const unsigned long long bm = __ballot(sup);
          if (lane == 0) smask[row] = bm;
        }
      }
      __syncthreads();
      // ---- C: scalar greedy on the diag (wave 0) ----
      if (wv == 0) {
        const unsigned long long diag = smask[lane];
        unsigned long long avail = ca;
        unsigned long long local = 0ull, keptbits = 0ull;
        int kc = kept;
        while (avail != 0ull && kc < NS) {
          const int b = (int)__builtin_ctzll(avail);
          keptbits |= 1ull << b;
          kc++;
          local |= rdlane64(diag, b);        // row b of self-mask
          avail &= ~local;
          avail &= ~(1ull << b);
        }
        // parallel rank-compaction of kept entries
        if ((keptbits >> lane) & 1ull) {
          const int rk =
              (int)__builtin_popcountll(keptbits & ((1ull << lane) - 1ull));
          keptlist[kbase + rk] = base + lane;
          keptbox[kbase + rk] = chunkbox[lane];
        }
        if (lane == 0) s_kept = kc;
      }
      __syncthreads();
      kept = s_kept;
      // ---- D: filter future register candidates vs NEW keeps ----
      if (kept > kbase && alivebits != 0u) {
        for (int kk = kbase; kk < kept; ++kk) {
          const float4 bx = keptbox[kk];     // LDS broadcast
#pragma unroll
          for (int k = 0; k < 8; ++k) {
            if ((alivebits >> k) & 1u) {
              if (iou_gt(bx, obox[k])) alivebits &= ~(1u << k);
            }
          }
        }
      }
    }
    __syncthreads();   // protect chunkbox/s_ca/smask rewrite next round
  }

  // ---- output: parallel over 512 threads ----
  for (int t = tid; t < kept; t += 512) {
    const int i = keptlist[t];
    const unsigned long long ki = kg[i];
    const float4 bi = sb[i];
    const unsigned idx = (unsigned)ki;
    float* row = o + t * 7;
    row[0] = __uint_as_float(~(unsigned)(ki >> 32));
    row[1] = bi.x; row[2] = bi.y; row[3] = bi.z; row[4] = bi.w;
    row[5] = an[idx * 4 + 2];
    row[6] = an[idx * 4 + 3];
  }
  for (int t = kept * 7 + tid; t < NS * 7; t += 512) o[t] = 0.0f;
}

// --------------- fallback: fused sort + on-the-fly scan (no d_ws) -------------
__global__ __launch_bounds__(1024)
void nms_fused_kernel(const float* __restrict__ scores,
                      const float4* __restrict__ boxes,
                      const float* __restrict__ anchors,
                      float* __restrict__ out, int N, int NS) {
  __shared__ unsigned long long keys[4096];
  __shared__ int s_m;
  if (N > 4096) return;
  const int img = blockIdx.x;
  const int tid = threadIdx.x;
  const float* sc = scores + (size_t)img * N;
  const float4* bx = boxes + (size_t)img * N;
  if (tid == 0) s_m = 0;
  __syncthreads();
  int cnt = 0;
  for (int i = tid; i < N; i += blockDim.x) {
    float s = sc[i];
    keys[i] = ((unsigned long long)(~__float_as_uint(s)) << 32) | (unsigned)i;
    if (s > kScoreT) cnt++;
  }
  if (cnt) atomicAdd(&s_m, cnt);
  __syncthreads();
  for (int k = 2; k <= N; k <<= 1) {
    for (int j = k >> 1; j > 0; j >>= 1) {
      for (int i = tid; i < N; i += blockDim.x) {
        int ixj = i ^ j;
        if (ixj > i) {
          unsigned long long a = keys[i];
          unsigned long long b = keys[ixj];
          bool up = ((i & k) == 0);
          if (up ? (a > b) : (a < b)) { keys[i] = b; keys[ixj] = a; }
        }
      }
      __syncthreads();
    }
  }
  if (tid >= 64) return;
  const int lane = tid;
  const int m = s_m;
  const int nw = (m + 63) >> 6;
  const float* an = anchors + (size_t)img * N * 4;
  float* o = out + (size_t)img * NS * 7;
  unsigned long long remv = 0ull;
  int kept = 0;
  for (int i = 0; i < m && kept < NS; ++i) {
    unsigned long long rw = __shfl(remv, i >> 6, 64);
    if ((rw >> (i & 63)) & 1ull) continue;
    unsigned long long ki = keys[i];
    float4 bi = bx[(unsigned)ki];
    if (lane == 0) {
      unsigned idx = (unsigned)ki;
      float* row = o + kept * 7;
      row[0] = __uint_as_float(~(unsigned)(ki >> 32));
      row[1] = bi.x; row[2] = bi.y; row[3] = bi.z; row[4] = bi.w;
      row[5] = an[idx * 4 + 2];
      row[6] = an[idx * 4 + 3];
    }
    kept++;
    for (int w2 = i >> 6; w2 < nw; ++w2) {
      int j = (w2 << 6) | lane;
      bool sup = false;
      if (j > i && j < m) sup = iou_gt(bi, bx[(unsigned)keys[j]]);
      unsigned long long bm = __ballot(sup);
      if (lane == w2) remv |= bm;
    }
  }
  for (int t = kept * 7 + lane; t < NS * 7; t += 64) o[t] = 0.0f;
}

extern "C" void kernel_launch(void* const* d_in, const int* in_sizes, int n_in,
                              void* d_out, int out_size, void* d_ws, size_t ws_size,
                              hipStream_t stream) {
  const float* scores = (const float*)d_in[0];
  const float4* boxes = (const float4*)d_in[1];
  const float* anchors = (const float*)d_in[2];
  float* out = (float*)d_out;
  const int B = 8;
  const int N = in_sizes[0] / B;      // 4096 boxes/image
  const int NS = out_size / (B * 7);  // 300 samples

  const size_t nTot = (size_t)B * (size_t)N;
  const size_t keysB = nTot * 8;
  const size_t sboxB = nTot * 16;
  const size_t mcntB = 256;
  const size_t need = keysB + sboxB + mcntB;

  if (ws_size >= need && (N % 256) == 0 && N >= 256 && N <= 4096 &&
      NS <= kMaxKeep) {
    char* p = (char*)d_ws;
    unsigned long long* skeys = (unsigned long long*)p; p += keysB;
    float4* sboxes = (float4*)p;                         p += sboxB;
    int* Mcnt = (int*)p;

    const int totalRows = B * N;
    const int rankBlocks = totalRows / 4;  // 256 thr = 4 waves per block
    nms_rank_kernel<<<rankBlocks + B, 256, 0, stream>>>(scores, boxes, skeys,
                                                        sboxes, Mcnt, N,
                                                        rankBlocks);
    nms_keep_kernel<<<B, 512, 0, stream>>>(skeys, sboxes, Mcnt, anchors, out,
                                           N, NS);
  } else {
    nms_fused_kernel<<<B, 1024, 0, stream>>>(scores, boxes, anchors, out, N, NS);
  }
}

// Round 11
// 176.733 us; speedup vs baseline: 1.4033x; 1.4033x over previous
//
#include <hip/hip_runtime.h>

static constexpr float kIouT = 0.35f;
static constexpr float kScoreT = 0.5f;
static constexpr int kMaxKeep = 512;

// Bit-exact mirror of the reference IoU (no FMA contraction) — mask kernel.
__device__ __forceinline__ float iou_f(const float4 a, const float4 b) {
  float areaA = __fmul_rn(a.z - a.x, a.w - a.y);
  float areaB = __fmul_rn(b.z - b.x, b.w - b.y);
  float iy1 = fmaxf(a.x, b.x);
  float ix1 = fmaxf(a.y, b.y);
  float iy2 = fminf(a.z, b.z);
  float ix2 = fminf(a.w, b.w);
  float dy = fmaxf(iy2 - iy1, 0.0f);
  float dx = fmaxf(ix2 - ix1, 0.0f);
  float inter = __fmul_rn(dy, dx);
  float uni = (areaA + areaB) - inter;
  return (uni > 0.0f) ? __fdiv_rn(inter, uni) : 0.0f;
}

// Decision-exact "iou > T" (quick reject, no division unless overlapping).
// Validated bit-exact end-to-end in round 9 (absmax = 0).
__device__ __forceinline__ bool iou_gt(const float4 a, const float4 b) {
  const float iy1 = fmaxf(a.x, b.x), ix1 = fmaxf(a.y, b.y);
  const float iy2 = fminf(a.z, b.z), ix2 = fminf(a.w, b.w);
  const float dy = iy2 - iy1, dx = ix2 - ix1;
  if (!(dy > 0.0f && dx > 0.0f)) return false;
  const float inter = __fmul_rn(dy, dx);
  const float aA = __fmul_rn(a.z - a.x, a.w - a.y);
  const float aB = __fmul_rn(b.z - b.x, b.w - b.y);
  const float uni = (aA + aB) - inter;
  return (uni > 0.0f) && (__fdiv_rn(inter, uni) > kIouT);
}

// 64-bit cross-lane pull with UNIFORM lane index (v_readlane).
__device__ __forceinline__ unsigned long long rdlane64(unsigned long long v,
                                                       int l) {
  unsigned lo = (unsigned)__builtin_amdgcn_readlane((int)(unsigned)v, l);
  unsigned hi = (unsigned)__builtin_amdgcn_readlane((int)(unsigned)(v >> 32), l);
  return ((unsigned long long)hi << 32) | lo;
}
__device__ __forceinline__ float rdlane_f(float v, int l) {
  return __int_as_float(__builtin_amdgcn_readlane(__float_as_int(v), l));
}

// ------- kernel 1 — rank (counting) sort of the VALID prefix (+count fold) ----
// [round-7 proven form]
__global__ __launch_bounds__(256)
void nms_rank_kernel(const float* __restrict__ scores,
                     const float4* __restrict__ boxes,
                     unsigned long long* __restrict__ skeys,
                     float4* __restrict__ sboxes,
                     int* __restrict__ Mcnt, int N, int rankBlocks) {
  const int tid = threadIdx.x;
  const int lane = tid & 63;
  if ((int)blockIdx.x >= rankBlocks) {   // ---- count mode ----
    __shared__ int part[4];
    const int img = blockIdx.x - rankBlocks;
    const int wv = tid >> 6;
    const float4* sc4 = (const float4*)(scores + (size_t)img * N);
    int c = 0;
    for (int q = tid; q < (N >> 2); q += 256) {
      float4 v = sc4[q];
      c += (v.x > kScoreT) + (v.y > kScoreT) + (v.z > kScoreT) + (v.w > kScoreT);
    }
#pragma unroll
    for (int off = 1; off < 64; off <<= 1) c += __shfl_xor(c, off, 64);
    if (lane == 0) part[wv] = c;
    __syncthreads();
    if (tid == 0) Mcnt[img] = part[0] + part[1] + part[2] + part[3];
    return;
  }
  // ---- rank mode ----
  const int wid = (int)(((unsigned)blockIdx.x * blockDim.x + tid) >> 6);
  const int img = wid / N;
  const int row = wid - img * N;
  const float* sc = scores + (size_t)img * N;
  const float si = sc[row];
  if (!(si > kScoreT)) return;
  const float4* sc4 = (const float4*)sc;
  int cnt = 0;
  for (int q = lane; q < (N >> 2); q += 64) {   // coalesced, L1/L2-resident
    const float4 v = sc4[q];
    const int j = q << 2;
    cnt += (v.x > si) + (v.y > si) + (v.z > si) + (v.w > si);
    if (v.x == si && j < row) cnt++;
    if (v.y == si && j + 1 < row) cnt++;
    if (v.z == si && j + 2 < row) cnt++;
    if (v.w == si && j + 3 < row) cnt++;
  }
#pragma unroll
  for (int off = 1; off < 64; off <<= 1) cnt += __shfl_xor(cnt, off, 64);
  if (lane == 0) {
    skeys[(size_t)img * N + cnt] =
        ((unsigned long long)(~__float_as_uint(si)) << 32) | (unsigned)row;
    sboxes[(size_t)img * N + cnt] = boxes[(size_t)img * N + row];
  }
}

// ------------- kernel 2 — pairwise IoU suppression masks [round-7 form] ------
__global__ __launch_bounds__(256)
void nms_mask_kernel(const float4* __restrict__ sboxes,
                     const int* __restrict__ Mcnt,
                     unsigned long long* __restrict__ mask,
                     int N, int totalRows) {
  const int wid = (int)(((unsigned)blockIdx.x * blockDim.x + threadIdx.x) >> 6);
  const int lane = threadIdx.x & 63;
  if (wid >= totalRows) return;
  const int img = wid / N;
  const int row = wid - img * N;
  const int m = Mcnt[img];
  if (row >= m) return;
  const float4* sb = sboxes + (size_t)img * N;
  const float4 bi = sb[row];
  const int nw = (m + 63) >> 6;
  unsigned long long* mrow = mask + (size_t)wid * (size_t)(N >> 6);
  for (int w = row >> 6; w < nw; ++w) {
    int j = (w << 6) | lane;
    bool sup = false;
    if (j > row && j < m) sup = iou_f(bi, sb[j]) > kIouT;
    unsigned long long bm = __ballot(sup);
    if (lane == 0) mrow[w] = bm;
  }
}

// ------- kernel 3 — ballot-scan: zero memory on the greedy recurrence --------
// Per chunk c (64 candidates; each lane holds its candidate's box in regs,
// prefetched 3 chunks ahead):
//  * local word = rdlane64(remv,c) | nextw.  nextw came from chunk c-1's
//    on-the-fly ballots; remv words >= c carry chunk<=c-2 keeps' mask rows.
//  * greedy: per keep b -> broadcast box b (4x v_readlane, b uniform) ->
//    iou_gt vs own box -> __ballot (SGPR) -> s_or. ~100cy, register-only.
//  * pending mask-row loads (words >= c+1 of chunk c-1's keeps) are OR'd into
//    lane-owned remv AFTER the greedy: issued a full chunk ago -> latency
//    hidden. New keeps' rows issued now, applied next chunk.
//  * nextw for chunk c+1 computed by ballots vs the (prefetched) c+1 boxes.
// The mask matrix thus only feeds words with >=1 chunk of slack; words c and
// c+1 never touch memory.
__global__ __launch_bounds__(64, 1)
void nms_scan_kernel(const unsigned long long* __restrict__ skeys,
                     const float4* __restrict__ sboxes,
                     const int* __restrict__ Mcnt,
                     const unsigned long long* __restrict__ mask,
                     const float* __restrict__ anchors,
                     float* __restrict__ out, int N, int NS) {
  __shared__ int keptlist[kMaxKeep];
  const int img = blockIdx.x;
  const int lane = threadIdx.x;
  int m = Mcnt[img];
  if (m > N) m = N;
  if (m < 0) m = 0;
  const int nw = (m + 63) >> 6;
  const int stride = N >> 6;
  const unsigned long long* mbase = mask + (size_t)img * (size_t)N * stride;
  const unsigned long long* kg = skeys + (size_t)img * N;
  const float4* sb = sboxes + (size_t)img * N;
  const float* an = anchors + (size_t)img * (size_t)N * 4;
  float* o = out + (size_t)img * NS * 7;

  int kept = 0;
  if (m > 0) {
    auto bxload = [&](int cc) -> float4 {
      int idx = (cc << 6) + lane;
      if (idx >= m) idx = m - 1;     // clamped lanes masked off by limmask
      return sb[idx];
    };
    float4 bx0 = bxload(0);
    float4 bx1 = bxload(1);
    float4 bx2 = bxload(2);
    unsigned long long pend[16];     // in-flight kept-row words (static idx)
    int pendn = 0, pendc = 0;
    unsigned long long remv = 0ull, nextw = 0ull;

    for (int c = 0; c < nw && kept < NS; ++c) {
      const int cb = c << 6;
      unsigned long long local = rdlane64(remv, c) | nextw;
      const int rem = m - cb;
      unsigned long long avail = ~local;
      if (rem < 64) avail &= (1ull << rem) - 1ull;
      unsigned long long keptbits = 0ull;
      // ---- greedy: register/ballot only ----
      while (avail != 0ull && kept < NS) {
        const int b = (int)__builtin_ctzll(avail);
        keptlist[kept] = cb + b;     // all lanes, same addr & data
        kept++;
        keptbits |= 1ull << b;
        const float4 bb = {rdlane_f(bx0.x, b), rdlane_f(bx0.y, b),
                           rdlane_f(bx0.z, b), rdlane_f(bx0.w, b)};
        const bool sup = (lane > b) && iou_gt(bb, bx0);
        const unsigned long long rc = __ballot(sup);
        local |= rc;
        avail &= ~local;
        avail &= ~(1ull << b);
      }
      // ---- apply pending rows from chunk c-1 (issued a full chunk ago) ----
      {
        const bool lok = (lane >= pendc) && (lane < nw);
#pragma unroll
        for (int k = 0; k < 16; ++k)
          if (k < pendn && lok) remv |= pend[k];
      }
      // ---- issue this chunk's kept-row loads (overflow >16: immediate) ----
      unsigned long long kb = keptbits;
      int nk = (int)__popcll(keptbits);
      while (nk > 16) {              // rare
        int bs[16];
#pragma unroll
        for (int k = 0; k < 16; ++k) {
          bs[k] = (int)__builtin_ctzll(kb);
          kb &= kb - 1ull;
        }
        unsigned long long tt[16];
#pragma unroll
        for (int k = 0; k < 16; ++k)
          tt[k] = mbase[(size_t)(cb + bs[k]) * stride + lane];
        unsigned long long acc = 0ull;
#pragma unroll
        for (int k = 0; k < 16; ++k) acc |= tt[k];
        if (lane >= c && lane < nw) remv |= acc;
        nk -= 16;
      }
      pendn = nk;
      pendc = c;
      if (nk > 0) {
        int bs[16];
        int bcur = (int)__builtin_ctzll(kb);
#pragma unroll
        for (int k = 0; k < 16; ++k) {
          if (kb != 0ull) {
            bcur = (int)__builtin_ctzll(kb);
            kb &= kb - 1ull;
          }
          bs[k] = bcur;              // dup slots gated off at apply (k>=pendn)
        }
#pragma unroll
        for (int k = 0; k < 16; ++k)
          pend[k] = mbase[(size_t)(cb + bs[k]) * stride + lane];
      }
      // ---- next chunk's word via ballots (replaces row word c+1) ----
      nextw = 0ull;
      kb = keptbits;
      while (kb != 0ull) {
        const int b = (int)__builtin_ctzll(kb);
        kb &= kb - 1ull;
        const float4 bb = {rdlane_f(bx0.x, b), rdlane_f(bx0.y, b),
                           rdlane_f(bx0.z, b), rdlane_f(bx0.w, b)};
        nextw |= __ballot(iou_gt(bb, bx1));
      }
      // ---- rotate box prefetch pipeline ----
      bx0 = bx1;
      bx1 = bx2;
      bx2 = bxload(c + 3);
    }
  }

  __syncthreads();  // drain keptlist LDS writes
  for (int t = lane; t < kept; t += 64) {
    const int i = keptlist[t];
    const unsigned long long ki = kg[i];
    const float4 bi = sb[i];
    const unsigned idx = (unsigned)ki;
    float* row = o + t * 7;
    row[0] = __uint_as_float(~(unsigned)(ki >> 32));
    row[1] = bi.x; row[2] = bi.y; row[3] = bi.z; row[4] = bi.w;
    row[5] = an[idx * 4 + 2];
    row[6] = an[idx * 4 + 3];
  }
  for (int t = kept * 7 + lane; t < NS * 7; t += 64) o[t] = 0.0f;
}

// --------------- fallback: fused sort + on-the-fly scan (no d_ws) -------------
__global__ __launch_bounds__(1024)
void nms_fused_kernel(const float* __restrict__ scores,
                      const float4* __restrict__ boxes,
                      const float* __restrict__ anchors,
                      float* __restrict__ out, int N, int NS) {
  __shared__ unsigned long long keys[4096];
  __shared__ int s_m;
  if (N > 4096) return;
  const int img = blockIdx.x;
  const int tid = threadIdx.x;
  const float* sc = scores + (size_t)img * N;
  const float4* bx = boxes + (size_t)img * N;
  if (tid == 0) s_m = 0;
  __syncthreads();
  int cnt = 0;
  for (int i = tid; i < N; i += blockDim.x) {
    float s = sc[i];
    keys[i] = ((unsigned long long)(~__float_as_uint(s)) << 32) | (unsigned)i;
    if (s > kScoreT) cnt++;
  }
  if (cnt) atomicAdd(&s_m, cnt);
  __syncthreads();
  for (int k = 2; k <= N; k <<= 1) {
    for (int j = k >> 1; j > 0; j >>= 1) {
      for (int i = tid; i < N; i += blockDim.x) {
        int ixj = i ^ j;
        if (ixj > i) {
          unsigned long long a = keys[i];
          unsigned long long b = keys[ixj];
          bool up = ((i & k) == 0);
          if (up ? (a > b) : (a < b)) { keys[i] = b; keys[ixj] = a; }
        }
      }
      __syncthreads();
    }
  }
  if (tid >= 64) return;
  const int lane = tid;
  const int m = s_m;
  const int nw = (m + 63) >> 6;
  const float* an = anchors + (size_t)img * N * 4;
  float* o = out + (size_t)img * NS * 7;
  unsigned long long remv = 0ull;
  int kept = 0;
  for (int i = 0; i < m && kept < NS; ++i) {
    unsigned long long rw = __shfl(remv, i >> 6, 64);
    if ((rw >> (i & 63)) & 1ull) continue;
    unsigned long long ki = keys[i];
    float4 bi = bx[(unsigned)ki];
    if (lane == 0) {
      unsigned idx = (unsigned)ki;
      float* row = o + kept * 7;
      row[0] = __uint_as_float(~(unsigned)(ki >> 32));
      row[1] = bi.x; row[2] = bi.y; row[3] = bi.z; row[4] = bi.w;
      row[5] = an[idx * 4 + 2];
      row[6] = an[idx * 4 + 3];
    }
    kept++;
    for (int w2 = i >> 6; w2 < nw; ++w2) {
      int j = (w2 << 6) | lane;
      bool sup = false;
      if (j > i && j < m) sup = iou_gt(bi, bx[(unsigned)keys[j]]);
      unsigned long long bm = __ballot(sup);
      if (lane == w2) remv |= bm;
    }
  }
  for (int t = kept * 7 + lane; t < NS * 7; t += 64) o[t] = 0.0f;
}

extern "C" void kernel_launch(void* const* d_in, const int* in_sizes, int n_in,
                              void* d_out, int out_size, void* d_ws, size_t ws_size,
                              hipStream_t stream) {
  const float* scores = (const float*)d_in[0];
  const float4* boxes = (const float4*)d_in[1];
  const float* anchors = (const float*)d_in[2];
  float* out = (float*)d_out;
  const int B = 8;
  const int N = in_sizes[0] / B;      // 4096 boxes/image
  const int NS = out_size / (B * 7);  // 300 samples

  const size_t nTot = (size_t)B * (size_t)N;
  const size_t keysB = nTot * 8;
  const size_t sboxB = nTot * 16;
  const size_t mcntB = 256;
  const size_t maskB = nTot * (size_t)(N >> 6) * 8;
  const size_t need = keysB + sboxB + mcntB + maskB;

  if (ws_size >= need && (N % 256) == 0 && N >= 256 && N <= 4096 &&
      NS <= kMaxKeep) {
    char* p = (char*)d_ws;
    unsigned long long* skeys = (unsigned long long*)p; p += keysB;
    float4* sboxes = (float4*)p;                         p += sboxB;
    int* Mcnt = (int*)p;                                 p += mcntB;
    unsigned long long* mask = (unsigned long long*)p;

    const int totalRows = B * N;
    const int rankBlocks = totalRows / 4;  // 256 thr = 4 waves per block
    nms_rank_kernel<<<rankBlocks + B, 256, 0, stream>>>(scores, boxes, skeys,
                                                        sboxes, Mcnt, N,
                                                        rankBlocks);
    nms_mask_kernel<<<rankBlocks, 256, 0, stream>>>(sboxes, Mcnt, mask, N,
                                                    totalRows);
    nms_scan_kernel<<<B, 64, 0, stream>>>(skeys, sboxes, Mcnt, mask, anchors,
                                          out, N, NS);
  } else {
    nms_fused_kernel<<<B, 1024, 0, stream>>>(scores, boxes, anchors, out, N, NS);
  }
}

// Round 12
// 136.514 us; speedup vs baseline: 1.8168x; 1.2946x over previous
//
#include <hip/hip_runtime.h>

static constexpr float kIouT = 0.35f;
static constexpr float kScoreT = 0.5f;
static constexpr int kMaxKeep = 512;
static constexpr int kWaves = 16;          // 1024 threads
static constexpr int kProd = kWaves - 1;   // waves 0..14 produce; wave 15 consumes

// Decision-exact "iou > T" (quick reject; division only for overlapping pairs).
// Validated bit-exact end-to-end in rounds 9/10 (absmax = 0).
__device__ __forceinline__ bool iou_gt(const float4 a, const float4 b) {
  const float iy1 = fmaxf(a.x, b.x), ix1 = fmaxf(a.y, b.y);
  const float iy2 = fminf(a.z, b.z), ix2 = fminf(a.w, b.w);
  const float dy = iy2 - iy1, dx = ix2 - ix1;
  if (!(dy > 0.0f && dx > 0.0f)) return false;
  const float inter = __fmul_rn(dy, dx);
  const float aA = __fmul_rn(a.z - a.x, a.w - a.y);
  const float aB = __fmul_rn(b.z - b.x, b.w - b.y);
  const float uni = (aA + aB) - inter;
  return (uni > 0.0f) && (__fdiv_rn(inter, uni) > kIouT);
}

// Cross-lane pulls with UNIFORM lane index (v_readlane, no LDS crossbar).
__device__ __forceinline__ unsigned long long rdlane64(unsigned long long v,
                                                       int l) {
  unsigned lo = (unsigned)__builtin_amdgcn_readlane((int)(unsigned)v, l);
  unsigned hi = (unsigned)__builtin_amdgcn_readlane((int)(unsigned)(v >> 32), l);
  return ((unsigned long long)hi << 32) | lo;
}
__device__ __forceinline__ float rdlane_f(float v, int l) {
  return __int_as_float(__builtin_amdgcn_readlane(__float_as_int(v), l));
}
__device__ __forceinline__ float4 rdlane_box(const float4 v, int l) {
  return {rdlane_f(v.x, l), rdlane_f(v.y, l), rdlane_f(v.z, l),
          rdlane_f(v.w, l)};
}

// ------- kernel 1 — rank (counting) sort of the VALID prefix (+count fold) ----
// [round-7 proven form]
__global__ __launch_bounds__(256)
void nms_rank_kernel(const float* __restrict__ scores,
                     const float4* __restrict__ boxes,
                     unsigned long long* __restrict__ skeys,
                     float4* __restrict__ sboxes,
                     int* __restrict__ Mcnt, int N, int rankBlocks) {
  const int tid = threadIdx.x;
  const int lane = tid & 63;
  if ((int)blockIdx.x >= rankBlocks) {   // ---- count mode ----
    __shared__ int part[4];
    const int img = blockIdx.x - rankBlocks;
    const int wv = tid >> 6;
    const float4* sc4 = (const float4*)(scores + (size_t)img * N);
    int c = 0;
    for (int q = tid; q < (N >> 2); q += 256) {
      float4 v = sc4[q];
      c += (v.x > kScoreT) + (v.y > kScoreT) + (v.z > kScoreT) + (v.w > kScoreT);
    }
#pragma unroll
    for (int off = 1; off < 64; off <<= 1) c += __shfl_xor(c, off, 64);
    if (lane == 0) part[wv] = c;
    __syncthreads();
    if (tid == 0) Mcnt[img] = part[0] + part[1] + part[2] + part[3];
    return;
  }
  // ---- rank mode ----
  const int wid = (int)(((unsigned)blockIdx.x * blockDim.x + tid) >> 6);
  const int img = wid / N;
  const int row = wid - img * N;
  const float* sc = scores + (size_t)img * N;
  const float si = sc[row];
  if (!(si > kScoreT)) return;
  const float4* sc4 = (const float4*)sc;
  int cnt = 0;
  for (int q = lane; q < (N >> 2); q += 64) {   // coalesced, L1/L2-resident
    const float4 v = sc4[q];
    const int j = q << 2;
    cnt += (v.x > si) + (v.y > si) + (v.z > si) + (v.w > si);
    if (v.x == si && j < row) cnt++;
    if (v.y == si && j + 1 < row) cnt++;
    if (v.z == si && j + 2 < row) cnt++;
    if (v.w == si && j + 3 < row) cnt++;
  }
#pragma unroll
  for (int off = 1; off < 64; off <<= 1) cnt += __shfl_xor(cnt, off, 64);
  if (lane == 0) {
    skeys[(size_t)img * N + cnt] =
        ((unsigned long long)(~__float_as_uint(si)) << 32) | (unsigned)row;
    sboxes[(size_t)img * N + cnt] = boxes[(size_t)img * N + row];
  }
}

// ------- kernel 2 — fused wave-specialized NMS (mask kernel DELETED) ---------
// One block per image; boxes in LDS; zero global memory in the recurrence.
// Period c (one barrier each):
//   consumer (wave 15): greedy on chunk c using per-lane diag regs (round-7
//     chain, ~40cy/keep); per NEW keep, one ballot vs chunk c+1 boxes (regs)
//     builds nextw (carried in register into period c+1).
//   producers (waves 0..14): (a) self-mask diag words of chunk c+1 (readlane
//     broadcast of per-lane next-chunk boxes, ballots, lane0 -> smaskb parity
//     buffer); (b) ballots of COMMITTED keeps (ordinals p,p+15,..) vs chunk
//     c+1 -> atomicOr into supw parity slot.
// Race-freedom: smaskb/supw/s_keptarr are parity-indexed (write slot != any
// read slot within a period; read slots written in the PREVIOUS period,
// barrier-separated). keptlist entries read by producers are >=1 period old.
// supw slot is zeroed by the consumer the period it is read; re-OR'd one
// period later. Coverage: keep at chunk c0 suppresses chunk c0 via diag,
// chunk c0+1 via consumer nextw, chunks >= c0+2 via producer supw (committed
// from period c0+1 onward).
__global__ __launch_bounds__(1024, 1)
void nms_fused_scan(const unsigned long long* __restrict__ skeys,
                    const float4* __restrict__ sboxes,
                    const int* __restrict__ Mcnt,
                    const float* __restrict__ anchors,
                    float* __restrict__ out, int N, int NS) {
  __shared__ float4 cbox[4096];                   // 64 KiB
  __shared__ unsigned long long smaskb[2][64];    // parity diag buffers
  __shared__ unsigned int supw[2][2];             // parity {lo,hi} words
  __shared__ int keptlist[kMaxKeep];
  __shared__ int s_keptarr[2];                    // parity committed counts
  __shared__ int s_done, s_final;
  const int img = blockIdx.x;
  const int tid = threadIdx.x;
  const int lane = tid & 63;
  const int wv = tid >> 6;
  int m = Mcnt[img];
  if (m > N) m = N;
  if (m < 0) m = 0;
  const int nw = (m + 63) >> 6;
  const unsigned long long* kg = skeys + (size_t)img * N;
  const float4* sb = sboxes + (size_t)img * N;
  const float* an = anchors + (size_t)img * (size_t)N * 4;
  float* o = out + (size_t)img * NS * 7;

  // ---- prologue ----
  for (int q = tid; q < m; q += 1024) cbox[q] = sb[q];
  if (tid == 0) {
    supw[0][0] = supw[0][1] = 0u;
    supw[1][0] = supw[1][1] = 0u;
    s_keptarr[0] = 0; s_keptarr[1] = 0;
    s_done = 0; s_final = 0;
  }
  __syncthreads();
  if (m > 0) {  // self-mask of chunk 0: 16 waves x 4 rows
    const float4 my0 = cbox[min(lane, m - 1)];
#pragma unroll
    for (int rr = 0; rr < 4; ++rr) {
      const int r = (wv << 2) + rr;
      const float4 br = rdlane_box(my0, r);
      const bool sup = (lane > r) && (lane < m) && iou_gt(br, my0);
      const unsigned long long bm = __ballot(sup);
      if (lane == 0) smaskb[0][r] = bm;
    }
  }
  __syncthreads();

  // ---- main loop ----
  int kept = 0;                      // consumer-local (uniform in wave 15)
  unsigned long long nextw = 0ull;   // consumer carry: K_c ballots vs c+1
  float4 mybox = {0, 0, 0, 0}, nbox = {0, 0, 0, 0};
  for (int c = 0; c < nw; ++c) {
    const int cb = c << 6;
    const bool hasNext = (c + 1) < nw;
    if (wv == kProd) {
      // ================= consumer =================
      if (c == 0) mybox = cbox[min(lane, m - 1)];
      if (hasNext) nbox = cbox[min(cb + 64 + lane, m - 1)];
      const unsigned long long diag = smaskb[c & 1][lane];
      const unsigned long long lw =
          ((unsigned long long)supw[c & 1][1] << 32) | supw[c & 1][0];
      if (lane == 0) { supw[c & 1][0] = 0u; supw[c & 1][1] = 0u; }  // recycle
      const int rem = m - cb;
      unsigned long long avail = ~(lw | nextw);
      if (rem < 64) avail &= (1ull << rem) - 1ull;
      unsigned long long keptbits = 0ull;
      while (avail != 0ull && kept < NS) {        // proven ~40cy/keep chain
        const int b = (int)__builtin_ctzll(avail);
        if (lane == 0) keptlist[kept] = cb + b;
        kept++;
        keptbits |= 1ull << b;
        const unsigned long long rc = rdlane64(diag, b);
        avail &= ~rc;
        avail &= ~(1ull << b);
      }
      nextw = 0ull;
      if (hasNext) {                              // one ballot per NEW keep
        unsigned long long kb2 = keptbits;
        while (kb2 != 0ull) {
          const int b = (int)__builtin_ctzll(kb2);
          kb2 &= kb2 - 1ull;
          const float4 bb = rdlane_box(mybox, b);
          nextw |= __ballot(iou_gt(bb, nbox));
        }
      }
      mybox = nbox;
      if (lane == 0) {
        s_keptarr[(c + 1) & 1] = kept;   // commit for next period's producers
        s_final = kept;
        if (kept >= NS) s_done = 1;
      }
    } else if (hasNext) {
      // ================= producers =================
      const int p = wv;                           // 0..14
      const int nb64 = cb + 64;
      const float4 pn = cbox[min(nb64 + lane, m - 1)];
      for (int r = p; r < 64; r += kProd) {       // diag rows of chunk c+1
        const float4 br = rdlane_box(pn, r);
        const bool sup = (lane > r) && (nb64 + lane < m) && iou_gt(br, pn);
        const unsigned long long bm = __ballot(sup);
        if (lane == 0) smaskb[(c + 1) & 1][r] = bm;
      }
      const int committed = s_keptarr[c & 1];     // keeps from chunks <= c-1
      unsigned long long acc = 0ull;
      for (int o2 = p; o2 < committed; o2 += kProd) {
        const float4 kbx = cbox[keptlist[o2]];    // LDS broadcast
        acc |= __ballot(iou_gt(kbx, pn));
      }
      if (acc != 0ull && lane == 0) {
        atomicOr(&supw[(c + 1) & 1][0], (unsigned)acc);
        atomicOr(&supw[(c + 1) & 1][1], (unsigned)(acc >> 32));
      }
    }
    __syncthreads();
    if (s_done != 0) break;
  }

  // ---- epilogue: parallel output over 1024 threads ----
  const int K = s_final;
  for (int t = tid; t < K; t += 1024) {
    const int i = keptlist[t];
    const unsigned long long ki = kg[i];
    const float4 bi = cbox[i];
    const unsigned idx = (unsigned)ki;
    float* row = o + t * 7;
    row[0] = __uint_as_float(~(unsigned)(ki >> 32));
    row[1] = bi.x; row[2] = bi.y; row[3] = bi.z; row[4] = bi.w;
    row[5] = an[idx * 4 + 2];
    row[6] = an[idx * 4 + 3];
  }
  for (int t = K * 7 + tid; t < NS * 7; t += 1024) o[t] = 0.0f;
}

// --------------- fallback: fused sort + on-the-fly scan (no d_ws) -------------
__global__ __launch_bounds__(1024)
void nms_fused_kernel(const float* __restrict__ scores,
                      const float4* __restrict__ boxes,
                      const float* __restrict__ anchors,
                      float* __restrict__ out, int N, int NS) {
  __shared__ unsigned long long keys[4096];
  __shared__ int s_m;
  if (N > 4096) return;
  const int img = blockIdx.x;
  const int tid = threadIdx.x;
  const float* sc = scores + (size_t)img * N;
  const float4* bx = boxes + (size_t)img * N;
  if (tid == 0) s_m = 0;
  __syncthreads();
  int cnt = 0;
  for (int i = tid; i < N; i += blockDim.x) {
    float s = sc[i];
    keys[i] = ((unsigned long long)(~__float_as_uint(s)) << 32) | (unsigned)i;
    if (s > kScoreT) cnt++;
  }
  if (cnt) atomicAdd(&s_m, cnt);
  __syncthreads();
  for (int k = 2; k <= N; k <<= 1) {
    for (int j = k >> 1; j > 0; j >>= 1) {
      for (int i = tid; i < N; i += blockDim.x) {
        int ixj = i ^ j;
        if (ixj > i) {
          unsigned long long a = keys[i];
          unsigned long long b = keys[ixj];
          bool up = ((i & k) == 0);
          if (up ? (a > b) : (a < b)) { keys[i] = b; keys[ixj] = a; }
        }
      }
      __syncthreads();
    }
  }
  if (tid >= 64) return;
  const int lane = tid;
  const int m = s_m;
  const int nw = (m + 63) >> 6;
  const float* an = anchors + (size_t)img * N * 4;
  float* o = out + (size_t)img * NS * 7;
  unsigned long long remv = 0ull;
  int kept = 0;
  for (int i = 0; i < m && kept < NS; ++i) {
    unsigned long long rw = __shfl(remv, i >> 6, 64);
    if ((rw >> (i & 63)) & 1ull) continue;
    unsigned long long ki = keys[i];
    float4 bi = bx[(unsigned)ki];
    if (lane == 0) {
      unsigned idx = (unsigned)ki;
      float* row = o + kept * 7;
      row[0] = __uint_as_float(~(unsigned)(ki >> 32));
      row[1] = bi.x; row[2] = bi.y; row[3] = bi.z; row[4] = bi.w;
      row[5] = an[idx * 4 + 2];
      row[6] = an[idx * 4 + 3];
    }
    kept++;
    for (int w2 = i >> 6; w2 < nw; ++w2) {
      int j = (w2 << 6) | lane;
      bool sup = false;
      if (j > i && j < m) sup = iou_gt(bi, bx[(unsigned)keys[j]]);
      unsigned long long bm = __ballot(sup);
      if (lane == w2) remv |= bm;
    }
  }
  for (int t = kept * 7 + lane; t < NS * 7; t += 64) o[t] = 0.0f;
}

extern "C" void kernel_launch(void* const* d_in, const int* in_sizes, int n_in,
                              void* d_out, int out_size, void* d_ws, size_t ws_size,
                              hipStream_t stream) {
  const float* scores = (const float*)d_in[0];
  const float4* boxes = (const float4*)d_in[1];
  const float* anchors = (const float*)d_in[2];
  float* out = (float*)d_out;
  const int B = 8;
  const int N = in_sizes[0] / B;      // 4096 boxes/image
  const int NS = out_size / (B * 7);  // 300 samples

  const size_t nTot = (size_t)B * (size_t)N;
  const size_t keysB = nTot * 8;
  const size_t sboxB = nTot * 16;
  const size_t mcntB = 256;
  const size_t need = keysB + sboxB + mcntB;   // no mask matrix anymore

  if (ws_size >= need && (N % 256) == 0 && N >= 256 && N <= 4096 &&
      NS <= kMaxKeep) {
    char* p = (char*)d_ws;
    unsigned long long* skeys = (unsigned long long*)p; p += keysB;
    float4* sboxes = (float4*)p;                         p += sboxB;
    int* Mcnt = (int*)p;

    const int totalRows = B * N;
    const int rankBlocks = totalRows / 4;  // 256 thr = 4 waves per block
    nms_rank_kernel<<<rankBlocks + B, 256, 0, stream>>>(scores, boxes, skeys,
                                                        sboxes, Mcnt, N,
                                                        rankBlocks);
    nms_fused_scan<<<B, 1024, 0, stream>>>(skeys, sboxes, Mcnt, anchors, out,
                                           N, NS);
  } else {
    nms_fused_kernel<<<B, 1024, 0, stream>>>(scores, boxes, anchors, out, N, NS);
  }
}

// Round 13
// 121.468 us; speedup vs baseline: 2.0418x; 1.1239x over previous
//
#include <hip/hip_runtime.h>

static constexpr float kIouT = 0.35f;
static constexpr float kScoreT = 0.5f;
static constexpr int kMaxKeep = 512;

// Decision-exact "iou > T" (quick reject; division only for overlapping pairs).
// Validated bit-exact end-to-end (absmax = 0) in rounds 9/10/11.
__device__ __forceinline__ bool iou_gt(const float4 a, const float4 b) {
  const float iy1 = fmaxf(a.x, b.x), ix1 = fmaxf(a.y, b.y);
  const float iy2 = fminf(a.z, b.z), ix2 = fminf(a.w, b.w);
  const float dy = iy2 - iy1, dx = ix2 - ix1;
  if (!(dy > 0.0f && dx > 0.0f)) return false;
  const float inter = __fmul_rn(dy, dx);
  const float aA = __fmul_rn(a.z - a.x, a.w - a.y);
  const float aB = __fmul_rn(b.z - b.x, b.w - b.y);
  const float uni = (aA + aB) - inter;
  return (uni > 0.0f) && (__fdiv_rn(inter, uni) > kIouT);
}

// 64-bit cross-lane pull with UNIFORM lane index (v_readlane).
__device__ __forceinline__ unsigned long long rdlane64(unsigned long long v,
                                                       int l) {
  unsigned lo = (unsigned)__builtin_amdgcn_readlane((int)(unsigned)v, l);
  unsigned hi = (unsigned)__builtin_amdgcn_readlane((int)(unsigned)(v >> 32), l);
  return ((unsigned long long)hi << 32) | lo;
}

// ------- kernel 1 — rank (counting) sort of the VALID prefix (+count fold) ----
// [round-7 proven form]
__global__ __launch_bounds__(256)
void nms_rank_kernel(const float* __restrict__ scores,
                     const float4* __restrict__ boxes,
                     unsigned long long* __restrict__ skeys,
                     float4* __restrict__ sboxes,
                     int* __restrict__ Mcnt, int N, int rankBlocks) {
  const int tid = threadIdx.x;
  const int lane = tid & 63;
  if ((int)blockIdx.x >= rankBlocks) {   // ---- count mode ----
    __shared__ int part[4];
    const int img = blockIdx.x - rankBlocks;
    const int wv = tid >> 6;
    const float4* sc4 = (const float4*)(scores + (size_t)img * N);
    int c = 0;
    for (int q = tid; q < (N >> 2); q += 256) {
      float4 v = sc4[q];
      c += (v.x > kScoreT) + (v.y > kScoreT) + (v.z > kScoreT) + (v.w > kScoreT);
    }
#pragma unroll
    for (int off = 1; off < 64; off <<= 1) c += __shfl_xor(c, off, 64);
    if (lane == 0) part[wv] = c;
    __syncthreads();
    if (tid == 0) Mcnt[img] = part[0] + part[1] + part[2] + part[3];
    return;
  }
  // ---- rank mode ----
  const int wid = (int)(((unsigned)blockIdx.x * blockDim.x + tid) >> 6);
  const int img = wid / N;
  const int row = wid - img * N;
  const float* sc = scores + (size_t)img * N;
  const float si = sc[row];
  if (!(si > kScoreT)) return;
  const float4* sc4 = (const float4*)sc;
  int cnt = 0;
  for (int q = lane; q < (N >> 2); q += 64) {   // coalesced, L1/L2-resident
    const float4 v = sc4[q];
    const int j = q << 2;
    cnt += (v.x > si) + (v.y > si) + (v.z > si) + (v.w > si);
    if (v.x == si && j < row) cnt++;
    if (v.y == si && j + 1 < row) cnt++;
    if (v.z == si && j + 2 < row) cnt++;
    if (v.w == si && j + 3 < row) cnt++;
  }
#pragma unroll
  for (int off = 1; off < 64; off <<= 1) cnt += __shfl_xor(cnt, off, 64);
  if (lane == 0) {
    skeys[(size_t)img * N + cnt] =
        ((unsigned long long)(~__float_as_uint(si)) << 32) | (unsigned)row;
    sboxes[(size_t)img * N + cnt] = boxes[(size_t)img * N + row];
  }
}

// ------------- kernel 2 — suppression masks, quick-reject IoU ---------------
// [round-7 form; iou_f>T replaced by decision-exact iou_gt: ~95% of pairs
//  skip the v_div sequence]
__global__ __launch_bounds__(256)
void nms_mask_kernel(const float4* __restrict__ sboxes,
                     const int* __restrict__ Mcnt,
                     unsigned long long* __restrict__ mask,
                     int N, int totalRows) {
  const int wid = (int)(((unsigned)blockIdx.x * blockDim.x + threadIdx.x) >> 6);
  const int lane = threadIdx.x & 63;
  if (wid >= totalRows) return;
  const int img = wid / N;
  const int row = wid - img * N;
  const int m = Mcnt[img];
  if (row >= m) return;
  const float4* sb = sboxes + (size_t)img * N;
  const float4 bi = sb[row];
  const int nw = (m + 63) >> 6;
  unsigned long long* mrow = mask + (size_t)wid * (size_t)(N >> 6);
  for (int w = row >> 6; w < nw; ++w) {
    int j = (w << 6) | lane;
    bool sup = false;
    if (j > row && j < m) sup = iou_gt(bi, sb[j]);
    unsigned long long bm = __ballot(sup);
    if (lane == 0) mrow[w] = bm;
  }
}

// ------- kernel 3 — scan: reg diag + next-word pipeline, 2-chunk-deferred ----
// Round-7 greedy chain (proven ~40cy/keep) with its two latency exposures
// removed:
//  * ndg pipeline prefetches word c+1 of chunk-c rows: chunk-c keeps suppress
//    chunk c+1 via register rdlane64 (nextw), no memory on that edge.
//  * kept-row batches (words >= c+2) are issued at chunk c into a PARITY
//    buffer (pendA/pendB, no register copies) and applied at chunk c+2 —
//    ~2 chunk-periods of slack hides the L3/cross-XCD round trip.
// Apply gate: lane >= issuing chunk (mask rows are written only for
// w >= row-chunk; earlier words are uninitialized) and lane < nw.
__global__ __launch_bounds__(64, 1)
void nms_scan_kernel(const unsigned long long* __restrict__ skeys,
                     const float4* __restrict__ sboxes,
                     const int* __restrict__ Mcnt,
                     const unsigned long long* __restrict__ mask,
                     const float* __restrict__ anchors,
                     float* __restrict__ out, int N, int NS) {
  __shared__ int keptlist[kMaxKeep];
  const int img = blockIdx.x;
  const int lane = threadIdx.x;
  int m = Mcnt[img];
  if (m > N) m = N;
  if (m < 0) m = 0;
  const int nw = (m + 63) >> 6;
  const int stride = N >> 6;
  const unsigned long long* mbase = mask + (size_t)img * (size_t)N * stride;
  const unsigned long long* kg = skeys + (size_t)img * N;
  const float4* sb = sboxes + (size_t)img * N;
  const float* an = anchors + (size_t)img * (size_t)N * 4;
  float* o = out + (size_t)img * NS * 7;

  int kept = 0;
  if (m > 0) {
    // diag (word cc) and next-word (word cc+1) of row cc*64+lane, clamped;
    // clamped/tail garbage is never readlane'd (avail limited to rows < m).
    auto dgload = [&](int cc) -> unsigned long long {
      const int cl = cc < (nw - 1) ? cc : (nw - 1);
      return mbase[(size_t)((cl << 6) + lane) * stride + cl];
    };
    auto ndload = [&](int cc) -> unsigned long long {
      const int cl = cc < (nw - 1) ? cc : (nw - 1);
      const int w = (cl + 1) < nw ? (cl + 1) : (nw - 1);
      return mbase[(size_t)((cl << 6) + lane) * stride + w];
    };
    unsigned long long dg0 = dgload(0), dg1 = dgload(1), dg2 = dgload(2);
    unsigned long long nd0 = ndload(0), nd1 = ndload(1), nd2 = ndload(2);
    unsigned long long pendA[16], pendB[16];   // parity batch buffers
    int pnA = 0, pcA = 0, pnB = 0, pcB = 0;
    unsigned long long remv = 0ull, nextw = 0ull;

    auto applyP = [&](unsigned long long (&pend)[16], int pn, int pc) {
      const bool lok = (lane >= pc) && (lane < nw);
#pragma unroll
      for (int k = 0; k < 16; ++k)
        if (k < pn && lok) remv |= pend[k];
    };
    auto issueP = [&](unsigned long long (&pend)[16], unsigned long long kb,
                      int nk, int cb) {
      int bs[16];
      int bcur = (int)__builtin_ctzll(kb | 1ull);  // safe init
#pragma unroll
      for (int k = 0; k < 16; ++k) {
        if (kb != 0ull) {
          bcur = (int)__builtin_ctzll(kb);
          kb &= kb - 1ull;
        }
        bs[k] = bcur;                  // dup slots gated off at apply (k>=pn)
      }
#pragma unroll
      for (int k = 0; k < 16; ++k)
        pend[k] = mbase[(size_t)(cb + bs[k]) * stride + lane];
    };

    for (int c = 0; c < nw && kept < NS; ++c) {
      const int cb = c << 6;
      // ---- apply the batch issued 2 chunks ago (parity c&1) ----
      if ((c & 1) == 0) { applyP(pendA, pnA, pcA); pnA = 0; }
      else              { applyP(pendB, pnB, pcB); pnB = 0; }
      // ---- greedy on chunk c (register-only chain) ----
      unsigned long long local = rdlane64(remv, c) | nextw;
      const int rem = m - cb;
      unsigned long long avail = ~local;
      if (rem < 64) avail &= (1ull << rem) - 1ull;
      unsigned long long keptbits = 0ull;
      const int keptbase = kept;
      while (avail != 0ull && kept < NS) {
        const int b = (int)__builtin_ctzll(avail);
        keptbits |= 1ull << b;
        kept++;
        const unsigned long long rc = rdlane64(dg0, b);
        local |= rc;
        avail &= ~local;
        avail &= ~(1ull << b);
      }
      // keptlist writes (off the serial chain)
      if (lane == 0) {
        unsigned long long kl = keptbits;
        int kc = keptbase;
        while (kl != 0ull) {
          const int b = (int)__builtin_ctzll(kl);
          kl &= kl - 1ull;
          keptlist[kc++] = cb + b;
        }
      }
      // ---- nextw: chunk-c keeps suppress chunk c+1 via registers ----
      nextw = 0ull;
      {
        unsigned long long kb = keptbits;
        while (kb != 0ull) {
          const int b = (int)__builtin_ctzll(kb);
          kb &= kb - 1ull;
          nextw |= rdlane64(nd0, b);
        }
      }
      // ---- issue this chunk's kept-row batch (words >= c+2 slack path) ----
      if (keptbits != 0ull && (kept < NS || c + 1 < nw)) {
        unsigned long long kb = keptbits;
        int nk = (int)__popcll(keptbits);
        while (nk > 16) {              // rare overflow: immediate, waited
          unsigned long long tt[16];
          int bs[16];
#pragma unroll
          for (int k = 0; k < 16; ++k) {
            bs[k] = (int)__builtin_ctzll(kb);
            kb &= kb - 1ull;
          }
#pragma unroll
          for (int k = 0; k < 16; ++k)
            tt[k] = mbase[(size_t)(cb + bs[k]) * stride + lane];
          unsigned long long acc = 0ull;
#pragma unroll
          for (int k = 0; k < 16; ++k) acc |= tt[k];
          if (lane >= c && lane < nw) remv |= acc;
          nk -= 16;
        }
        if ((c & 1) == 0) { issueP(pendA, kb, nk, cb); pnA = nk; pcA = c; }
        else              { issueP(pendB, kb, nk, cb); pnB = nk; pcB = c; }
      }
      // ---- rotate prefetch pipelines ----
      dg0 = dg1; dg1 = dg2; dg2 = dgload(c + 3);
      nd0 = nd1; nd1 = nd2; nd2 = ndload(c + 3);
    }
  }

  __syncthreads();  // drain keptlist LDS writes
  for (int t = lane; t < kept; t += 64) {
    const int i = keptlist[t];
    const unsigned long long ki = kg[i];
    const float4 bi = sb[i];
    const unsigned idx = (unsigned)ki;
    float* row = o + t * 7;
    row[0] = __uint_as_float(~(unsigned)(ki >> 32));
    row[1] = bi.x; row[2] = bi.y; row[3] = bi.z; row[4] = bi.w;
    row[5] = an[idx * 4 + 2];
    row[6] = an[idx * 4 + 3];
  }
  for (int t = kept * 7 + lane; t < NS * 7; t += 64) o[t] = 0.0f;
}

// --------------- fallback: fused sort + on-the-fly scan (no d_ws) -------------
__global__ __launch_bounds__(1024)
void nms_fused_kernel(const float* __restrict__ scores,
                      const float4* __restrict__ boxes,
                      const float* __restrict__ anchors,
                      float* __restrict__ out, int N, int NS) {
  __shared__ unsigned long long keys[4096];
  __shared__ int s_m;
  if (N > 4096) return;
  const int img = blockIdx.x;
  const int tid = threadIdx.x;
  const float* sc = scores + (size_t)img * N;
  const float4* bx = boxes + (size_t)img * N;
  if (tid == 0) s_m = 0;
  __syncthreads();
  int cnt = 0;
  for (int i = tid; i < N; i += blockDim.x) {
    float s = sc[i];
    keys[i] = ((unsigned long long)(~__float_as_uint(s)) << 32) | (unsigned)i;
    if (s > kScoreT) cnt++;
  }
  if (cnt) atomicAdd(&s_m, cnt);
  __syncthreads();
  for (int k = 2; k <= N; k <<= 1) {
    for (int j = k >> 1; j > 0; j >>= 1) {
      for (int i = tid; i < N; i += blockDim.x) {
        int ixj = i ^ j;
        if (ixj > i) {
          unsigned long long a = keys[i];
          unsigned long long b = keys[ixj];
          bool up = ((i & k) == 0);
          if (up ? (a > b) : (a < b)) { keys[i] = b; keys[ixj] = a; }
        }
      }
      __syncthreads();
    }
  }
  if (tid >= 64) return;
  const int lane = tid;
  const int m = s_m;
  const int nw = (m + 63) >> 6;
  const float* an = anchors + (size_t)img * N * 4;
  float* o = out + (size_t)img * NS * 7;
  unsigned long long remv = 0ull;
  int kept = 0;
  for (int i = 0; i < m && kept < NS; ++i) {
    unsigned long long rw = __shfl(remv, i >> 6, 64);
    if ((rw >> (i & 63)) & 1ull) continue;
    unsigned long long ki = keys[i];
    float4 bi = bx[(unsigned)ki];
    if (lane == 0) {
      unsigned idx = (unsigned)ki;
      float* row = o + kept * 7;
      row[0] = __uint_as_float(~(unsigned)(ki >> 32));
      row[1] = bi.x; row[2] = bi.y; row[3] = bi.z; row[4] = bi.w;
      row[5] = an[idx * 4 + 2];
      row[6] = an[idx * 4 + 3];
    }
    kept++;
    for (int w2 = i >> 6; w2 < nw; ++w2) {
      int j = (w2 << 6) | lane;
      bool sup = false;
      if (j > i && j < m) sup = iou_gt(bi, bx[(unsigned)keys[j]]);
      unsigned long long bm = __ballot(sup);
      if (lane == w2) remv |= bm;
    }
  }
  for (int t = kept * 7 + lane; t < NS * 7; t += 64) o[t] = 0.0f;
}

extern "C" void kernel_launch(void* const* d_in, const int* in_sizes, int n_in,
                              void* d_out, int out_size, void* d_ws, size_t ws_size,
                              hipStream_t stream) {
  const float* scores = (const float*)d_in[0];
  const float4* boxes = (const float4*)d_in[1];
  const float* anchors = (const float*)d_in[2];
  float* out = (float*)d_out;
  const int B = 8;
  const int N = in_sizes[0] / B;      // 4096 boxes/image
  const int NS = out_size / (B * 7);  // 300 samples

  const size_t nTot = (size_t)B * (size_t)N;
  const size_t keysB = nTot * 8;
  const size_t sboxB = nTot * 16;
  const size_t mcntB = 256;
  const size_t maskB = nTot * (size_t)(N >> 6) * 8;
  const size_t need = keysB + sboxB + mcntB + maskB;

  if (ws_size >= need && (N % 256) == 0 && N >= 256 && N <= 4096 &&
      NS <= kMaxKeep) {
    char* p = (char*)d_ws;
    unsigned long long* skeys = (unsigned long long*)p; p += keysB;
    float4* sboxes = (float4*)p;                         p += sboxB;
    int* Mcnt = (int*)p;                                 p += mcntB;
    unsigned long long* mask = (unsigned long long*)p;

    const int totalRows = B * N;
    const int rankBlocks = totalRows / 4;  // 256 thr = 4 waves per block
    nms_rank_kernel<<<rankBlocks + B, 256, 0, stream>>>(scores, boxes, skeys,
                                                        sboxes, Mcnt, N,
                                                        rankBlocks);
    nms_mask_kernel<<<rankBlocks, 256, 0, stream>>>(sboxes, Mcnt, mask, N,
                                                    totalRows);
    nms_scan_kernel<<<B, 64, 0, stream>>>(skeys, sboxes, Mcnt, mask, anchors,
                                          out, N, NS);
  } else {
    nms_fused_kernel<<<B, 1024, 0, stream>>>(scores, boxes, anchors, out, N, NS);
  }
}

// Round 14
// 101.835 us; speedup vs baseline: 2.4355x; 1.1928x over previous
//
#include <hip/hip_runtime.h>

static constexpr float kIouT = 0.35f;
static constexpr float kScoreT = 0.5f;
static constexpr int kMaxKeep = 512;

// Decision-exact "iou > T" (quick reject; division only for overlapping pairs).
// Validated bit-exact end-to-end (absmax = 0) in rounds 9-12.
__device__ __forceinline__ bool iou_gt(const float4 a, const float4 b) {
  const float iy1 = fmaxf(a.x, b.x), ix1 = fmaxf(a.y, b.y);
  const float iy2 = fminf(a.z, b.z), ix2 = fminf(a.w, b.w);
  const float dy = iy2 - iy1, dx = ix2 - ix1;
  if (!(dy > 0.0f && dx > 0.0f)) return false;
  const float inter = __fmul_rn(dy, dx);
  const float aA = __fmul_rn(a.z - a.x, a.w - a.y);
  const float aB = __fmul_rn(b.z - b.x, b.w - b.y);
  const float uni = (aA + aB) - inter;
  return (uni > 0.0f) && (__fdiv_rn(inter, uni) > kIouT);
}

// 64-bit cross-lane pull with UNIFORM lane index (v_readlane).
__device__ __forceinline__ unsigned long long rdlane64(unsigned long long v,
                                                       int l) {
  unsigned lo = (unsigned)__builtin_amdgcn_readlane((int)(unsigned)v, l);
  unsigned hi = (unsigned)__builtin_amdgcn_readlane((int)(unsigned)(v >> 32), l);
  return ((unsigned long long)hi << 32) | lo;
}

// ------- kernel 1 — rank (counting) sort of the VALID prefix (+count fold) ----
// [round-7 proven form, unchanged]
__global__ __launch_bounds__(256)
void nms_rank_kernel(const float* __restrict__ scores,
                     const float4* __restrict__ boxes,
                     unsigned long long* __restrict__ skeys,
                     float4* __restrict__ sboxes,
                     int* __restrict__ Mcnt, int N, int rankBlocks) {
  const int tid = threadIdx.x;
  const int lane = tid & 63;
  if ((int)blockIdx.x >= rankBlocks) {   // ---- count mode ----
    __shared__ int part[4];
    const int img = blockIdx.x - rankBlocks;
    const int wv = tid >> 6;
    const float4* sc4 = (const float4*)(scores + (size_t)img * N);
    int c = 0;
    for (int q = tid; q < (N >> 2); q += 256) {
      float4 v = sc4[q];
      c += (v.x > kScoreT) + (v.y > kScoreT) + (v.z > kScoreT) + (v.w > kScoreT);
    }
#pragma unroll
    for (int off = 1; off < 64; off <<= 1) c += __shfl_xor(c, off, 64);
    if (lane == 0) part[wv] = c;
    __syncthreads();
    if (tid == 0) Mcnt[img] = part[0] + part[1] + part[2] + part[3];
    return;
  }
  // ---- rank mode ----
  const int wid = (int)(((unsigned)blockIdx.x * blockDim.x + tid) >> 6);
  const int img = wid / N;
  const int row = wid - img * N;
  const float* sc = scores + (size_t)img * N;
  const float si = sc[row];
  if (!(si > kScoreT)) return;
  const float4* sc4 = (const float4*)sc;
  int cnt = 0;
  for (int q = lane; q < (N >> 2); q += 64) {   // coalesced, L1/L2-resident
    const float4 v = sc4[q];
    const int j = q << 2;
    cnt += (v.x > si) + (v.y > si) + (v.z > si) + (v.w > si);
    if (v.x == si && j < row) cnt++;
    if (v.y == si && j + 1 < row) cnt++;
    if (v.z == si && j + 2 < row) cnt++;
    if (v.w == si && j + 3 < row) cnt++;
  }
#pragma unroll
  for (int off = 1; off < 64; off <<= 1) cnt += __shfl_xor(cnt, off, 64);
  if (lane == 0) {
    skeys[(size_t)img * N + cnt] =
        ((unsigned long long)(~__float_as_uint(si)) << 32) | (unsigned)row;
    sboxes[(size_t)img * N + cnt] = boxes[(size_t)img * N + row];
  }
}

// ------------- kernel 2 — suppression masks [round-7 form + 2 tweaks] --------
// (a) iou_gt quick-reject (skips v_div for ~95% of pairs);
// (b) NON-TEMPORAL stores: mask lines land clean in L3 instead of dirty in
//     the writer's XCD L2 — the scan's reads become ~600cy L3 hits instead
//     of ~1.5-2k cy cross-XCD dirty-line pulls.
__global__ __launch_bounds__(256)
void nms_mask_kernel(const float4* __restrict__ sboxes,
                     const int* __restrict__ Mcnt,
                     unsigned long long* __restrict__ mask,
                     int N, int totalRows) {
  const int wid = (int)(((unsigned)blockIdx.x * blockDim.x + threadIdx.x) >> 6);
  const int lane = threadIdx.x & 63;
  if (wid >= totalRows) return;
  const int img = wid / N;
  const int row = wid - img * N;
  const int m = Mcnt[img];
  if (row >= m) return;
  const float4* sb = sboxes + (size_t)img * N;
  const float4 bi = sb[row];
  const int nw = (m + 63) >> 6;
  unsigned long long* mrow = mask + (size_t)wid * (size_t)(N >> 6);
  for (int w = row >> 6; w < nw; ++w) {
    int j = (w << 6) | lane;
    bool sup = false;
    if (j > row && j < m) sup = iou_gt(bi, sb[j]);
    unsigned long long bm = __ballot(sup);
    if (lane == 0) __builtin_nontemporal_store(bm, &mrow[w]);
  }
}

// ------- kernel 3 — scan [EXACT round-7 structure; loads are non-temporal] ---
// Serial keep-chain: pure SALU/readlane (~40cy/keep). Per keep-bearing chunk,
// kept rows' mask words are OR'd into lane-owned remv via a 16-deep batch of
// unconditional clamp-indexed loads (indices in a statically unrolled array;
// exhausted slots repeat -> idempotent OR). One wait per batch.
__global__ __launch_bounds__(64, 1)
void nms_scan_kernel(const unsigned long long* __restrict__ skeys,
                     const float4* __restrict__ sboxes,
                     const int* __restrict__ Mcnt,
                     const unsigned long long* __restrict__ mask,
                     const float* __restrict__ anchors,
                     float* __restrict__ out, int N, int NS) {
  __shared__ int keptlist[kMaxKeep];
  const int img = blockIdx.x;
  const int lane = threadIdx.x;
  int m = Mcnt[img];
  if (m > N) m = N;
  if (m < 0) m = 0;
  const int nw = (m + 63) >> 6;        // <= 64 since m <= 4096
  const int stride = N >> 6;
  const unsigned long long* mbase = mask + (size_t)img * (size_t)N * stride;
  const unsigned long long* kg = skeys + (size_t)img * N;
  const float4* sb = sboxes + (size_t)img * N;
  const float* an = anchors + (size_t)img * (size_t)N * 4;
  float* o = out + (size_t)img * NS * 7;

  int kept = 0;
  unsigned long long remv = 0ull;

  if (m > 0) {
    // diag prefetch pipeline (word cc of row cc*64+lane), 3 chunks ahead;
    // index clamped so tail loads are valid (values unused past nw).
    auto dgload = [&](int cc) -> unsigned long long {
      const int cl = cc < (nw - 1) ? cc : (nw - 1);
      return __builtin_nontemporal_load(
          &mbase[(size_t)((cl << 6) + lane) * stride + cl]);
    };
    unsigned long long dg0 = dgload(0);
    unsigned long long dg1 = dgload(1);
    unsigned long long dg2 = dgload(2);

    for (int c = 0; c < nw && kept < NS; ++c) {
      const int cb = c << 6;
      unsigned long long local = rdlane64(remv, c);
      const int rem = m - cb;
      unsigned long long avail = ~local;
      if (rem < 64) avail &= (1ull << rem) - 1ull;
      unsigned long long keptbits = 0ull;
      const int keptbase = kept;
      // ---- serial greedy loop: pure scalar + readlane ----
      while (avail != 0ull && kept < NS) {
        const int b = (int)__builtin_ctzll(avail);
        keptbits |= 1ull << b;
        kept++;
        const unsigned long long rc = rdlane64(dg0, b);  // word c of row cb+b
        local |= rc;
        avail &= ~local;
        avail &= ~(1ull << b);
      }
      // rotate diag pipeline (issue next load before the delta waits)
      dg0 = dg1; dg1 = dg2; dg2 = dgload(c + 3);
      if (keptbits != 0ull) {
        // keptlist writes (off the serial chain)
        if (lane == 0) {
          unsigned long long kl = keptbits;
          int kc = keptbase;
          while (kl != 0ull) {
            const int b = (int)__builtin_ctzll(kl);
            kl &= kl - 1ull;
            keptlist[kc++] = cb + b;
          }
        }
        // ---- delta: 16-deep unconditional clamp-indexed load batches ----
        if (kept < NS || c + 1 < nw) {   // skip only if nothing future needs it
          const bool lok = (lane > c) && (lane < nw);
          unsigned long long kb = keptbits;
          while (kb != 0ull) {
            int bs[16];
            int bcur = (int)__builtin_ctzll(kb);
#pragma unroll
            for (int k = 0; k < 16; ++k) {
              if (kb != 0ull) {
                bcur = (int)__builtin_ctzll(kb);
                kb &= kb - 1ull;
              }
              bs[k] = bcur;            // duplicates when exhausted (idempotent)
            }
            unsigned long long t[16];
#pragma unroll
            for (int k = 0; k < 16; ++k)
              t[k] = __builtin_nontemporal_load(
                  &mbase[(size_t)(cb + bs[k]) * stride + lane]);
            unsigned long long acc = 0ull;
#pragma unroll
            for (int k = 0; k < 16; ++k) acc |= t[k];
            if (lok) remv |= acc;
          }
        }
      }
    }
  }

  __syncthreads();  // drain keptlist LDS writes for all lanes
  // parallel output over the wave
  for (int t = lane; t < kept; t += 64) {
    const int i = keptlist[t];
    const unsigned long long ki = kg[i];
    const float4 bi = sb[i];
    const unsigned idx = (unsigned)ki;
    float* row = o + t * 7;
    row[0] = __uint_as_float(~(unsigned)(ki >> 32));
    row[1] = bi.x; row[2] = bi.y; row[3] = bi.z; row[4] = bi.w;
    row[5] = an[idx * 4 + 2];
    row[6] = an[idx * 4 + 3];
  }
  for (int t = kept * 7 + lane; t < NS * 7; t += 64) o[t] = 0.0f;
}

// --------------- fallback: fused sort + on-the-fly scan (no d_ws) -------------
__global__ __launch_bounds__(1024)
void nms_fused_kernel(const float* __restrict__ scores,
                      const float4* __restrict__ boxes,
                      const float* __restrict__ anchors,
                      float* __restrict__ out, int N, int NS) {
  __shared__ unsigned long long keys[4096];
  __shared__ int s_m;
  if (N > 4096) return;
  const int img = blockIdx.x;
  const int tid = threadIdx.x;
  const float* sc = scores + (size_t)img * N;
  const float4* bx = boxes + (size_t)img * N;
  if (tid == 0) s_m = 0;
  __syncthreads();
  int cnt = 0;
  for (int i = tid; i < N; i += blockDim.x) {
    float s = sc[i];
    keys[i] = ((unsigned long long)(~__float_as_uint(s)) << 32) | (unsigned)i;
    if (s > kScoreT) cnt++;
  }
  if (cnt) atomicAdd(&s_m, cnt);
  __syncthreads();
  for (int k = 2; k <= N; k <<= 1) {
    for (int j = k >> 1; j > 0; j >>= 1) {
      for (int i = tid; i < N; i += blockDim.x) {
        int ixj = i ^ j;
        if (ixj > i) {
          unsigned long long a = keys[i];
          unsigned long long b = keys[ixj];
          bool up = ((i & k) == 0);
          if (up ? (a > b) : (a < b)) { keys[i] = b; keys[ixj] = a; }
        }
      }
      __syncthreads();
    }
  }
  if (tid >= 64) return;
  const int lane = tid;
  const int m = s_m;
  const int nw = (m + 63) >> 6;
  const float* an = anchors + (size_t)img * N * 4;
  float* o = out + (size_t)img * NS * 7;
  unsigned long long remv = 0ull;
  int kept = 0;
  for (int i = 0; i < m && kept < NS; ++i) {
    unsigned long long rw = __shfl(remv, i >> 6, 64);
    if ((rw >> (i & 63)) & 1ull) continue;
    unsigned long long ki = keys[i];
    float4 bi = bx[(unsigned)ki];
    if (lane == 0) {
      unsigned idx = (unsigned)ki;
      float* row = o + kept * 7;
      row[0] = __uint_as_float(~(unsigned)(ki >> 32));
      row[1] = bi.x; row[2] = bi.y; row[3] = bi.z; row[4] = bi.w;
      row[5] = an[idx * 4 + 2];
      row[6] = an[idx * 4 + 3];
    }
    kept++;
    for (int w2 = i >> 6; w2 < nw; ++w2) {
      int j = (w2 << 6) | lane;
      bool sup = false;
      if (j > i && j < m) sup = iou_gt(bi, bx[(unsigned)keys[j]]);
      unsigned long long bm = __ballot(sup);
      if (lane == w2) remv |= bm;
    }
  }
  for (int t = kept * 7 + lane; t < NS * 7; t += 64) o[t] = 0.0f;
}

extern "C" void kernel_launch(void* const* d_in, const int* in_sizes, int n_in,
                              void* d_out, int out_size, void* d_ws, size_t ws_size,
                              hipStream_t stream) {
  const float* scores = (const float*)d_in[0];
  const float4* boxes = (const float4*)d_in[1];
  const float* anchors = (const float*)d_in[2];
  float* out = (float*)d_out;
  const int B = 8;
  const int N = in_sizes[0] / B;      // 4096 boxes/image
  const int NS = out_size / (B * 7);  // 300 samples

  const size_t nTot = (size_t)B * (size_t)N;
  const size_t keysB = nTot * 8;
  const size_t sboxB = nTot * 16;
  const size_t mcntB = 256;
  const size_t maskB = nTot * (size_t)(N >> 6) * 8;
  const size_t need = keysB + sboxB + mcntB + maskB;

  if (ws_size >= need && (N % 256) == 0 && N >= 256 && N <= 4096 &&
      NS <= kMaxKeep) {
    char* p = (char*)d_ws;
    unsigned long long* skeys = (unsigned long long*)p; p += keysB;
    float4* sboxes = (float4*)p;                         p += sboxB;
    int* Mcnt = (int*)p;                                 p += mcntB;
    unsigned long long* mask = (unsigned long long*)p;

    const int totalRows = B * N;
    const int rankBlocks = totalRows / 4;  // 256 thr = 4 waves per block
    nms_rank_kernel<<<rankBlocks + B, 256, 0, stream>>>(scores, boxes, skeys,
                                                        sboxes, Mcnt, N,
                                                        rankBlocks);
    nms_mask_kernel<<<rankBlocks, 256, 0, stream>>>(sboxes, Mcnt, mask, N,
                                                    totalRows);
    nms_scan_kernel<<<B, 64, 0, stream>>>(skeys, sboxes, Mcnt, mask, anchors,
                                          out, N, NS);
  } else {
    nms_fused_kernel<<<B, 1024, 0, stream>>>(scores, boxes, anchors, out, N, NS);
  }
}